// Round 7
// baseline (4139.719 us; speedup 1.0000x reference)
//
#include <hip/hip_runtime.h>

#define NT 1024
#define TSEQ 512

typedef float float2v __attribute__((ext_vector_type(2)));

__device__ __forceinline__ float sigmoid_(float x) { return 1.0f / (1.0f + __expf(-x)); }
__device__ __forceinline__ float tanh_(float x) { return 1.0f - 2.0f / (1.0f + __expf(2.0f * x)); }

// LDS-visibility-only barrier (validated rounds 2-6): drains lgkmcnt (ds ops,
// incl. ds_swizzle) but NOT vmcnt -> global prefetch loads / h-stores stay in
// flight. Layer boundaries use full __syncthreads() before hseq is re-read.
__device__ __forceinline__ void wg_barrier() {
    asm volatile("s_waitcnt lgkmcnt(0)" ::: "memory");
    __builtin_amdgcn_s_barrier();
}

// quad_perm DPP adds (VALU pipe): xor1 = [1,0,3,2] = 0xB1, xor2 = [2,3,0,1] = 0x4E
#define DPP_ADD(v, ctrl) ((v) + __int_as_float(__builtin_amdgcn_mov_dpp(__float_as_int(v), (ctrl), 0xF, 0xF, true)))
// xor-4 lane exchange via ds_swizzle BitMode: offset = (4<<10) | 0x1F
#define SWZ4_ADD(v) ((v) + __int_as_float(__builtin_amdgcn_ds_swizzle(__float_as_int(v), 0x101F)))

// ---------------- prep kernel ----------------
// Task map (main): tid = 8u + f  (u = unit 0..99, f = k-chunk 0..7, 25 k's each).
// k=200 image (per parity): chunks 0-3 = x-part, chunks 4-7 = h-part, each chunk
// padded to 28 floats (pads zero).
//   layer0   : chunk0 j<5 = x; chunks 1-3 zero; chunks 4-7 = h quarters
//   layers>=1: chunks 0-3 = x quarters (prev h); chunks 4-7 = h quarters
// Weight image per thread: 4 gates x 25 k = 12 float2 pairs (j0..23) + 1 scalar (j24).
// region A (float2): idx ((l*4+g)*12 + p)*800 + t ; region B (float): ((l*4+g))*800 + t
extern "C" __global__ void prep_weights(const float* __restrict__ Wih0,
                                        const float* __restrict__ Whh0,
                                        const float* __restrict__ WihL,
                                        const float* __restrict__ WhhL,
                                        float2* __restrict__ wA, float* __restrict__ wB) {
    int gid = blockIdx.x * 256 + threadIdx.x;   // (l*4+g)*800 + t ; total 16000
    if (gid >= 16000) return;
    int t = gid % 800;
    int lg = gid / 800;
    int g = lg & 3, l = lg >> 2;
    int u = t >> 3, f = t & 7;
    int row = g * 100 + u;
    float vv[25];
    for (int j = 0; j < 25; ++j) {
        float w = 0.f;
        if (l == 0) {
            if (f == 0) { if (j < 5) w = Wih0[row * 5 + j]; }
            else if (f >= 4) w = Whh0[row * 100 + 25 * (f - 4) + j];
        } else {
            if (f < 4) w = WihL[(l - 1) * 40000 + row * 100 + 25 * f + j];
            else       w = WhhL[(l - 1) * 40000 + row * 100 + 25 * (f - 4) + j];
        }
        vv[j] = w;
    }
    for (int p = 0; p < 12; ++p)
        wA[((size_t)lg * 12 + p) * 800 + t] = make_float2(vv[2 * p], vv[2 * p + 1]);
    wB[(size_t)lg * 800 + t] = vv[24];
}

// ---------------- main kernel ----------------
// ONE barrier per step. LDS image (448 floats):
//   [xA 0..111 | xB 112..223 | hA 224..335 | hB 336..447], chunk stride 28.
// Phase t: chunk f<4 reads x parity t&1; f>=4 reads h parity (t-1)&1.
// Writer (f==0) writes h(t) -> parity t&1. Lander (f==1) lands x(t+1) -> parity
// (t+1)&1 (values prefetched one full phase earlier). All writes disjoint from
// all reads within a phase -> single lgkm-only barrier is race-free.
template <bool FIRST, bool STORE>
__device__ void run_layer(const float2* __restrict__ wA, const float* __restrict__ wB,
                          const float* __restrict__ bL,
                          const float* __restrict__ xsrc, float* __restrict__ hdst,
                          int b, int tid, int u, int f, bool act,
                          float* __restrict__ lds) {
    // weights + biases -> registers
    float2v w[48]; float ws[4];
    float bi = 0.f, bf = 0.f, bg = 0.f, bo = 0.f;
    if (act) {
#pragma unroll
        for (int g = 0; g < 4; ++g) {
#pragma unroll
            for (int p = 0; p < 12; ++p) {
                float2 ww = wA[((size_t)g * 12 + p) * 800 + tid];
                w[g * 12 + p] = (float2v){ww.x, ww.y};
            }
            ws[g] = wB[(size_t)g * 800 + tid];
        }
        bi = bL[u]; bf = bL[100 + u]; bg = bL[200 + u]; bo = bL[300 + u];
    } else {
#pragma unroll
        for (int i = 0; i < 48; ++i) w[i] = (float2v){0.f, 0.f};
        ws[0] = ws[1] = ws[2] = ws[3] = 0.f;
    }

    // zero image (both parities, incl. pads)
    for (int i = tid; i < 448; i += NT) lds[i] = 0.f;
    __syncthreads();          // full drain: zeros + prev layer's hseq stores visible
    // stage x(0) -> parity 0
    if (FIRST) { if (tid < 5) lds[tid] = xsrc[(size_t)b * TSEQ * 5 + tid]; }
    else       { if (tid < 100) lds[28 * (tid / 25) + tid % 25] = xsrc[(size_t)b * TSEQ * 100 + tid]; }
    __syncthreads();

    bool lander = act && (f == 1) && (FIRST ? (u < 5) : true);
    int xoff = FIRST ? u : (28 * (u / 25) + u % 25);
    float pf = 0.f;
    if (lander) pf = FIRST ? xsrc[((size_t)b * TSEQ + 1) * 5 + u]
                           : xsrc[((size_t)b * TSEQ + 1) * 100 + u];
    bool writer = act && (f == 0);
    int hoff = 224 + 28 * (u / 25) + (u % 25);
    int cbase = (f < 4) ? (28 * f) : (224 + 28 * (f - 4));
    int fadd = (f < 4) ? 0 : 1;        // f>=4: parity (t+1)&1 == (t-1)&1
    size_t gbase = (size_t)b * TSEQ * 100 + u;
    float c = 0.f;

    for (int t = 0; t < TSEQ; ++t) {
        const float* xc = lds + cbase + (((t + fadd) & 1) * 112);
        const float4* xc4 = (const float4*)xc;
        float2v A0 = {0.f,0.f}, A1 = {0.f,0.f}, A2 = {0.f,0.f}, A3 = {0.f,0.f};
#pragma unroll
        for (int q = 0; q < 6; ++q) {
            float4 v = xc4[q];
            float2v lo = (float2v){v.x, v.y};
            float2v hi = (float2v){v.z, v.w};
            A0 = __builtin_elementwise_fma(w[2*q],      lo, A0);
            A0 = __builtin_elementwise_fma(w[2*q+1],    hi, A0);
            A1 = __builtin_elementwise_fma(w[12+2*q],   lo, A1);
            A1 = __builtin_elementwise_fma(w[12+2*q+1], hi, A1);
            A2 = __builtin_elementwise_fma(w[24+2*q],   lo, A2);
            A2 = __builtin_elementwise_fma(w[24+2*q+1], hi, A2);
            A3 = __builtin_elementwise_fma(w[36+2*q],   lo, A3);
            A3 = __builtin_elementwise_fma(w[36+2*q+1], hi, A3);
        }
        float x24 = xc[24];
        float s0 = fmaf(ws[0], x24, A0.x + A0.y);
        float s1 = fmaf(ws[1], x24, A1.x + A1.y);
        float s2 = fmaf(ws[2], x24, A2.x + A2.y);
        float s3 = fmaf(ws[3], x24, A3.x + A3.y);
        // 8-lane butterfly: 2 DPP rounds (VALU) + 1 ds_swizzle round
        s0 = DPP_ADD(s0, 0xB1); s1 = DPP_ADD(s1, 0xB1); s2 = DPP_ADD(s2, 0xB1); s3 = DPP_ADD(s3, 0xB1);
        s0 = DPP_ADD(s0, 0x4E); s1 = DPP_ADD(s1, 0x4E); s2 = DPP_ADD(s2, 0x4E); s3 = DPP_ADD(s3, 0x4E);
        s0 = SWZ4_ADD(s0); s1 = SWZ4_ADD(s1); s2 = SWZ4_ADD(s2); s3 = SWZ4_ADD(s3);
        // gates: redundant on all 8 lanes of the unit group (deterministic)
        float gi = sigmoid_(s0 + bi);
        float gf = sigmoid_(s1 + bf);
        float gg = tanh_(s2 + bg);
        float go = sigmoid_(s3 + bo);
        c = gf * c + gi * gg;
        float hv = go * tanh_(c);
        if (writer) {
            lds[hoff + (t & 1) * 112] = hv;
            if (STORE) hdst[gbase + (size_t)t * 100] = hv;   // fire-and-forget
        }
        if (lander) {
            lds[((t + 1) & 1) * 112 + xoff] = pf;            // land x(t+1)
            int tn = (t + 2 < TSEQ) ? (t + 2) : (TSEQ - 1);  // issue x(t+2)
            pf = FIRST ? xsrc[((size_t)b * TSEQ + tn) * 5 + u]
                       : xsrc[((size_t)b * TSEQ + tn) * 100 + u];
        }
        wg_barrier();   // single barrier: h(t) + x(t+1) visible; vmem stays in flight
    }
}

extern "C" __global__ void __launch_bounds__(NT, 4)
gesture_lstm_kernel(const float* __restrict__ x,
                    const float2* __restrict__ wA, const float* __restrict__ wB,
                    const float* __restrict__ b0, const float* __restrict__ bLv,
                    const float* __restrict__ gamma, const float* __restrict__ beta,
                    const float* __restrict__ rmean, const float* __restrict__ rvar,
                    const float* __restrict__ W1, const float* __restrict__ b1,
                    const float* __restrict__ W2, const float* __restrict__ b2,
                    const float* __restrict__ W3, const float* __restrict__ b3,
                    float* __restrict__ out, float* __restrict__ hseq) {
    __shared__ __align__(16) float lds[448];
    __shared__ __align__(16) float head[512];
    __shared__ __align__(16) float hw[10000];

    int tid = threadIdx.x;
    int b = blockIdx.x;
    int u = tid >> 3;         // unit (>=100 -> dummy group, isolated)
    int f = tid & 7;          // k-chunk
    bool act = (u < 100);

    run_layer<true,  true >(wA,             wB,            b0,         x,    hseq, b, tid, u, f, act, lds);
    run_layer<false, true >(wA + 1*38400,   wB + 1*3200,   bLv + 0,    hseq, hseq, b, tid, u, f, act, lds);
    run_layer<false, true >(wA + 2*38400,   wB + 2*3200,   bLv + 400,  hseq, hseq, b, tid, u, f, act, lds);
    run_layer<false, true >(wA + 3*38400,   wB + 3*3200,   bLv + 800,  hseq, hseq, b, tid, u, f, act, lds);
    run_layer<false, false>(wA + 4*38400,   wB + 4*3200,   bLv + 1200, hseq, hseq, b, tid, u, f, act, lds);

    // ---- head: BN (inference) -> FC1+ReLU -> FC2+ReLU -> FC3 ----
    // final h(511) lives at parity 1: lds[336 + 28*(u/25) + u%25]
    if (tid < 100) {
        float hv = lds[336 + 28 * (tid / 25) + tid % 25];
        head[tid] = (hv - rmean[tid]) * rsqrtf(rvar[tid] + 1e-5f) * gamma[tid] + beta[tid];
    }
    __syncthreads();

    for (int i = tid; i < 2500; i += NT) ((float4*)hw)[i] = ((const float4*)W1)[i];
    __syncthreads();
    if (tid < 100) {
        float acc = b1[tid];
#pragma unroll
        for (int k = 0; k < 100; ++k) acc = fmaf(hw[tid * 100 + k], head[k], acc);
        head[128 + tid] = fmaxf(acc, 0.0f);
    }
    __syncthreads();

    for (int i = tid; i < 2500; i += NT) ((float4*)hw)[i] = ((const float4*)W2)[i];
    __syncthreads();
    if (tid < 100) {
        float acc = b2[tid];
#pragma unroll
        for (int k = 0; k < 100; ++k) acc = fmaf(hw[tid * 100 + k], head[128 + k], acc);
        head[256 + tid] = fmaxf(acc, 0.0f);
    }
    __syncthreads();

    if (tid < 3) {
        float acc = b3[tid];
#pragma unroll
        for (int k = 0; k < 100; ++k) acc = fmaf(W3[tid * 100 + k], head[256 + k], acc);
        out[b * 3 + tid] = acc;
    }
}

extern "C" void kernel_launch(void* const* d_in, const int* in_sizes, int n_in,
                              void* d_out, int out_size, void* d_ws, size_t ws_size,
                              hipStream_t stream) {
    const float* x     = (const float*)d_in[0];
    const float* Wih0  = (const float*)d_in[1];
    const float* Whh0  = (const float*)d_in[2];
    const float* b0    = (const float*)d_in[3];
    const float* WihL  = (const float*)d_in[4];
    const float* WhhL  = (const float*)d_in[5];
    const float* bLv   = (const float*)d_in[6];
    const float* gamma = (const float*)d_in[7];
    const float* beta  = (const float*)d_in[8];
    const float* rmean = (const float*)d_in[9];
    const float* rvar  = (const float*)d_in[10];
    const float* W1    = (const float*)d_in[11];
    const float* b1    = (const float*)d_in[12];
    const float* W2    = (const float*)d_in[13];
    const float* b2    = (const float*)d_in[14];
    const float* W3    = (const float*)d_in[15];
    const float* b3    = (const float*)d_in[16];

    // ws layout (same 54.07 MB footprint as prior rounds):
    //   [0, 1.536 MB)      wA: 192000 float2 (pair weights)
    //   [1.536, 1.600 MB)  wB: 16000 float (j=24 scalars)
    //   [1.6384 MB, ...)   hseq: 256*512*100 fp32 = 52.4 MB
    float2* wA  = (float2*)d_ws;
    float*  wB  = (float*)((char*)d_ws + 1536000);
    float*  hseq = (float*)((char*)d_ws + 1638400);

    prep_weights<<<dim3(63), dim3(256), 0, stream>>>(Wih0, Whh0, WihL, WhhL, wA, wB);
    gesture_lstm_kernel<<<dim3(256), dim3(NT), 0, stream>>>(
        x, wA, wB, b0, bLv, gamma, beta, rmean, rvar, W1, b1, W2, b2, W3, b3,
        (float*)d_out, hseq);
}

// Round 8
// 2170.809 us; speedup vs baseline: 1.9070x; 1.9070x over previous
//
#include <hip/hip_runtime.h>

#define NT 1024
#define TSEQ 512

typedef float float2v __attribute__((ext_vector_type(2)));

__device__ __forceinline__ float sigmoid_(float x) { return 1.0f / (1.0f + __expf(-x)); }
__device__ __forceinline__ float tanh_(float x) { return 1.0f - 2.0f / (1.0f + __expf(2.0f * x)); }

// ---------------- prep kernel: pack weights into task-ordered image ----------------
// Task map (main kernel): f = tid/100 (k-chunk of 20), rg = tid%100 (unit; owns all
// 4 gate rows of unit rg). tid>=1000: zeros.
// wbuf float4 index: (l*20 + g*5 + q)*1024 + tid  ->  W[g*100+rg][20f+4q .. +3]
// Padded K=200 row image: layer0 = [x(5); h(100); 0(95)], layers>=1 = [x(100); h(100)].
// NOTE: layer0 chunks f>=6 are all-zero -> main kernel skips them (512 steps x 4
// chunks of pure-zero reads/MACs/partial-writes saved).
extern "C" __global__ void prep_weights(const float* __restrict__ Wih0,
                                        const float* __restrict__ Whh0,
                                        const float* __restrict__ WihL,
                                        const float* __restrict__ WhhL,
                                        float4* __restrict__ wbuf) {
    int gid = blockIdx.x * 256 + threadIdx.x;  // 5*20*1024 = 102400 total
    if (gid >= 102400) return;
    int tid = gid & 1023;
    int lgq = gid >> 10;
    int gq = lgq % 20;          // g*5 + q
    int l = lgq / 20;
    int g = gq / 5, q = gq % 5;
    float tmp[4] = {0.f, 0.f, 0.f, 0.f};
    if (tid < 1000) {
        int f = tid / 100, rg = tid % 100;
        int row = g * 100 + rg;
        int k0 = 20 * f + 4 * q;
        for (int c = 0; c < 4; ++c) {
            int k = k0 + c;
            float w = 0.f;
            if (l == 0) {
                if (k < 5) w = Wih0[row * 5 + k];
                else if (k < 105) w = Whh0[row * 100 + (k - 5)];
            } else {
                if (k < 100) w = WihL[(l - 1) * 40000 + row * 100 + k];
                else w = WhhL[(l - 1) * 40000 + row * 100 + (k - 100)];
            }
            tmp[c] = w;
        }
    }
    wbuf[gid] = make_float4(tmp[0], tmp[1], tmp[2], tmp[3]);
}

// ---------------- main kernel ----------------
// One block per batch element. Thread (f, rg) owns gates {i,f,g,o} of unit rg over
// k in [20f, 20f+20) — 80 weights (40 float2 pairs) in registers, pk_fma inner loop.
// r0 schedule preserved exactly (7 rounds of restructures all regressed):
// delayed h-store at phase top, register prefetch landed after combine,
// plain __syncthreads barriers. This round only deletes work:
//  - layer 0: skip the 4 all-zero k-chunks (tid>=600 idles through MAC)
//  - combine: even/odd dual-chain packed-f2v reduction (depth 9 -> ~5)
template <int IN, bool FIRST, bool STORE>
__device__ void run_layer(const float4* __restrict__ wl, const float* __restrict__ bL,
                          const float* __restrict__ xsrc, float* __restrict__ hdst,
                          int b, int tid, int f, int rg, bool real,
                          float* xh, float4* part4) {
    // weights -> registers: branch-free, constant dest indices
    float2v w[40];  // [g*10 + 2q] = k pair (4q,4q+1), [g*10+2q+1] = (4q+2,4q+3)
#pragma unroll
    for (int g = 0; g < 4; ++g) {
#pragma unroll
        for (int q = 0; q < 5; ++q) {
            float4 t = wl[(g * 5 + q) * 1024 + tid];
            w[g * 10 + 2 * q]     = (float2v){t.x, t.y};
            w[g * 10 + 2 * q + 1] = (float2v){t.z, t.w};
        }
    }
    // combine threads hold their unit's biases in registers
    float bi = 0.f, bf = 0.f, bg = 0.f, bo = 0.f;
    if (tid < 100) {
        bi = bL[tid]; bf = bL[100 + tid]; bg = bL[200 + tid]; bo = bL[300 + tid];
    }

    if (tid < 256) xh[tid] = 0.f;
    __syncthreads();
    if (FIRST) {
        if (tid < 5) xh[tid] = xsrc[b * TSEQ * 5 + tid];
    } else {
        if (tid < 25) ((float4*)xh)[tid] = ((const float4*)xsrc)[b * TSEQ * 25 + tid];
    }
    __syncthreads();

    const float4* xv4 = (const float4*)xh + f * 5;  // chunk base (dummies -> zeros at 200+)
    float c = 0.f, hprev = 0.f;

    // layer 0: chunks f>=6 are all-zero weights -> those threads skip MAC entirely
    bool mac = FIRST ? (tid < 600) : real;
    constexpr int NF = FIRST ? 6 : 10;   // partials summed in combine

    for (int t = 0; t < TSEQ; ++t) {
        // delayed h-store: issued at phase top so the barrier drain finds it done
        if (STORE) {
            if (tid < 100 && t > 0) hdst[(b * TSEQ + (t - 1)) * 100 + tid] = hprev;
        }
        // prefetch next-step input (landed after combine)
        int tn = (t + 1 < TSEQ) ? (t + 1) : (TSEQ - 1);
        float pfs = 0.f;
        float4 pf4 = {0.f, 0.f, 0.f, 0.f};
        if (FIRST) {
            if (tid >= 128 && tid < 133) pfs = xsrc[(b * TSEQ + tn) * 5 + (tid - 128)];
        } else {
            if (tid >= 128 && tid < 153) pf4 = ((const float4*)xsrc)[(b * TSEQ + tn) * 25 + (tid - 128)];
        }

        // 80 MACs as 40 v_pk_fma_f32
        if (mac) {
            float2v a0 = {0.f, 0.f}, a1 = {0.f, 0.f}, a2 = {0.f, 0.f}, a3 = {0.f, 0.f};
#pragma unroll
            for (int q = 0; q < 5; ++q) {
                float4 xq = xv4[q];
                float2v xlo = (float2v){xq.x, xq.y};
                float2v xhi = (float2v){xq.z, xq.w};
                a0 = __builtin_elementwise_fma(w[2 * q],      xlo, a0);
                a0 = __builtin_elementwise_fma(w[2 * q + 1],  xhi, a0);
                a1 = __builtin_elementwise_fma(w[10 + 2 * q],     xlo, a1);
                a1 = __builtin_elementwise_fma(w[10 + 2 * q + 1], xhi, a1);
                a2 = __builtin_elementwise_fma(w[20 + 2 * q],     xlo, a2);
                a2 = __builtin_elementwise_fma(w[20 + 2 * q + 1], xhi, a2);
                a3 = __builtin_elementwise_fma(w[30 + 2 * q],     xlo, a3);
                a3 = __builtin_elementwise_fma(w[30 + 2 * q + 1], xhi, a3);
            }
            part4[f * 100 + rg] = make_float4(a0.x + a0.y, a1.x + a1.y,
                                              a2.x + a2.y, a3.x + a3.y);
        }
        __syncthreads();

        // combine: thread rg<100 owns unit rg end-to-end.
        // Even/odd dual accumulation chains (packed f2v) halve the serial depth.
        if (tid < 100) {
            float4 p0 = part4[tid];
            float4 p1 = part4[100 + tid];
            float2v sAe = (float2v){p0.x, p0.y}, sBe = (float2v){p0.z, p0.w};
            float2v sAo = (float2v){p1.x, p1.y}, sBo = (float2v){p1.z, p1.w};
#pragma unroll
            for (int ff = 2; ff < NF; ff += 2) {
                float4 pe = part4[ff * 100 + tid];
                sAe += (float2v){pe.x, pe.y};
                sBe += (float2v){pe.z, pe.w};
                if (ff + 1 < NF) {
                    float4 po = part4[(ff + 1) * 100 + tid];
                    sAo += (float2v){po.x, po.y};
                    sBo += (float2v){po.z, po.w};
                }
            }
            float2v sA = sAe + sAo;
            float2v sB = sBe + sBo;
            float gi = sigmoid_(sA.x + bi);
            float gf = sigmoid_(sA.y + bf);
            float gg = tanh_(sB.x + bg);
            float go = sigmoid_(sB.y + bo);
            c = gf * c + gi * gg;
            float hv = go * tanh_(c);
            xh[IN + tid] = hv;
            hprev = hv;
        }
        // land prefetched x for t+1
        if (FIRST) {
            if (tid >= 128 && tid < 133) xh[tid - 128] = pfs;
        } else {
            if (tid >= 128 && tid < 153) ((float4*)xh)[tid - 128] = pf4;
        }
        __syncthreads();
    }
    if (STORE) {
        if (tid < 100) hdst[(b * TSEQ + TSEQ - 1) * 100 + tid] = hprev;
    }
}

extern "C" __global__ void __launch_bounds__(NT, 4)
gesture_lstm_kernel(const float* __restrict__ x,
                    const float4* __restrict__ wbuf,
                    const float* __restrict__ b0, const float* __restrict__ bLv,
                    const float* __restrict__ gamma, const float* __restrict__ beta,
                    const float* __restrict__ rmean, const float* __restrict__ rvar,
                    const float* __restrict__ W1, const float* __restrict__ b1,
                    const float* __restrict__ W2, const float* __restrict__ b2,
                    const float* __restrict__ W3, const float* __restrict__ b3,
                    float* __restrict__ out, float* __restrict__ hseq) {
    __shared__ __align__(16) float xh[256];
    __shared__ __align__(16) float4 part4[1000];
    __shared__ __align__(16) float hw[10000];

    int tid = threadIdx.x;
    int b = blockIdx.x;
    int f = tid / 100;   // 10 for dummies -> xv4 reads land in xh[200..220) (zeroed)
    int rg = tid % 100;
    bool real = tid < 1000;

    run_layer<5,   true,  true >(wbuf + 0 * 20480, b0,         x,    hseq, b, tid, f, rg, real, xh, part4);
    run_layer<100, false, true >(wbuf + 1 * 20480, bLv + 0,    hseq, hseq, b, tid, f, rg, real, xh, part4);
    run_layer<100, false, true >(wbuf + 2 * 20480, bLv + 400,  hseq, hseq, b, tid, f, rg, real, xh, part4);
    run_layer<100, false, true >(wbuf + 3 * 20480, bLv + 800,  hseq, hseq, b, tid, f, rg, real, xh, part4);
    run_layer<100, false, false>(wbuf + 4 * 20480, bLv + 1200, hseq, hseq, b, tid, f, rg, real, xh, part4);

    // ---- head: BN (inference) -> FC1+ReLU -> FC2+ReLU -> FC3 ----
    float* fcbuf = (float*)part4;
    if (tid < 100) {
        float hv = xh[100 + tid];
        xh[tid] = (hv - rmean[tid]) * rsqrtf(rvar[tid] + 1e-5f) * gamma[tid] + beta[tid];
    }
    __syncthreads();

    for (int i = tid; i < 2500; i += NT) ((float4*)hw)[i] = ((const float4*)W1)[i];
    __syncthreads();
    if (tid < 100) {
        float acc = b1[tid];
#pragma unroll
        for (int k = 0; k < 100; ++k) acc = fmaf(hw[tid * 100 + k], xh[k], acc);
        fcbuf[tid] = fmaxf(acc, 0.0f);
    }
    __syncthreads();

    for (int i = tid; i < 2500; i += NT) ((float4*)hw)[i] = ((const float4*)W2)[i];
    __syncthreads();
    if (tid < 100) {
        float acc = b2[tid];
#pragma unroll
        for (int k = 0; k < 100; ++k) acc = fmaf(hw[tid * 100 + k], fcbuf[k], acc);
        fcbuf[400 + tid] = fmaxf(acc, 0.0f);
    }
    __syncthreads();

    if (tid < 3) {
        float acc = b3[tid];
#pragma unroll
        for (int k = 0; k < 100; ++k) acc = fmaf(W3[tid * 100 + k], fcbuf[400 + k], acc);
        out[b * 3 + tid] = acc;
    }
}

extern "C" void kernel_launch(void* const* d_in, const int* in_sizes, int n_in,
                              void* d_out, int out_size, void* d_ws, size_t ws_size,
                              hipStream_t stream) {
    const float* x     = (const float*)d_in[0];
    const float* Wih0  = (const float*)d_in[1];
    const float* Whh0  = (const float*)d_in[2];
    const float* b0    = (const float*)d_in[3];
    const float* WihL  = (const float*)d_in[4];
    const float* WhhL  = (const float*)d_in[5];
    const float* bLv   = (const float*)d_in[6];
    const float* gamma = (const float*)d_in[7];
    const float* beta  = (const float*)d_in[8];
    const float* rmean = (const float*)d_in[9];
    const float* rvar  = (const float*)d_in[10];
    const float* W1    = (const float*)d_in[11];
    const float* b1    = (const float*)d_in[12];
    const float* W2    = (const float*)d_in[13];
    const float* b2    = (const float*)d_in[14];
    const float* W3    = (const float*)d_in[15];
    const float* b3    = (const float*)d_in[16];

    float4* wbuf = (float4*)d_ws;                       // 102400 float4 = 1.6375 MB
    float* hseq  = (float*)((char*)d_ws + 102400 * 16); // 256*512*100 fp32 = 52.4 MB

    prep_weights<<<dim3(400), dim3(256), 0, stream>>>(Wih0, Whh0, WihL, WhhL, wbuf);
    gesture_lstm_kernel<<<dim3(256), dim3(NT), 0, stream>>>(
        x, wbuf, b0, bLv, gamma, beta, rmean, rvar, W1, b1, W2, b2, W3, b3,
        (float*)d_out, hseq);
}

// Round 9
// 2106.271 us; speedup vs baseline: 1.9654x; 1.0306x over previous
//
#include <hip/hip_runtime.h>

#define NT 1024
#define TSEQ 512

typedef float float2v __attribute__((ext_vector_type(2)));

// raw v_rcp_f32 (1 ulp) — skips the Newton refinement of the '/' operator.
__device__ __forceinline__ float rcp_(float x) { return __builtin_amdgcn_rcpf(x); }
__device__ __forceinline__ float sigmoid_(float x) { return rcp_(1.0f + __expf(-x)); }
__device__ __forceinline__ float tanh_(float x) { return 1.0f - 2.0f * rcp_(1.0f + __expf(2.0f * x)); }

// ---------------- prep kernel: pack weights into task-ordered image ----------------
// Task map (main kernel): f = tid/100 (k-chunk of 20), rg = tid%100 (unit; owns all
// 4 gate rows of unit rg). tid>=1000: zeros.
// wbuf float4 index: (l*20 + g*5 + q)*1024 + tid  ->  W[g*100+rg][20f+4q .. +3]
// Padded K=200 row image: layer0 = [x(5); h(100); 0(95)], layers>=1 = [x(100); h(100)].
// NOTE: layer0 chunks f>=6 are all-zero -> main kernel skips them.
extern "C" __global__ void prep_weights(const float* __restrict__ Wih0,
                                        const float* __restrict__ Whh0,
                                        const float* __restrict__ WihL,
                                        const float* __restrict__ WhhL,
                                        float4* __restrict__ wbuf) {
    int gid = blockIdx.x * 256 + threadIdx.x;  // 5*20*1024 = 102400 total
    if (gid >= 102400) return;
    int tid = gid & 1023;
    int lgq = gid >> 10;
    int gq = lgq % 20;          // g*5 + q
    int l = lgq / 20;
    int g = gq / 5, q = gq % 5;
    float tmp[4] = {0.f, 0.f, 0.f, 0.f};
    if (tid < 1000) {
        int f = tid / 100, rg = tid % 100;
        int row = g * 100 + rg;
        int k0 = 20 * f + 4 * q;
        for (int c = 0; c < 4; ++c) {
            int k = k0 + c;
            float w = 0.f;
            if (l == 0) {
                if (k < 5) w = Wih0[row * 5 + k];
                else if (k < 105) w = Whh0[row * 100 + (k - 5)];
            } else {
                if (k < 100) w = WihL[(l - 1) * 40000 + row * 100 + k];
                else w = WhhL[(l - 1) * 40000 + row * 100 + (k - 100)];
            }
            tmp[c] = w;
        }
    }
    wbuf[gid] = make_float4(tmp[0], tmp[1], tmp[2], tmp[3]);
}

// ---------------- main kernel ----------------
// One block per batch element. Thread (f, rg) owns gates {i,f,g,o} of unit rg over
// k in [20f, 20f+20) — 80 weights (40 float2 pairs) in registers, pk_fma inner loop.
// r0 schedule preserved exactly (7 rounds of restructures all regressed):
// delayed h-store at phase top, register prefetch landed after combine,
// plain __syncthreads barriers. r8 additions kept: layer-0 zero-chunk skip, short
// combine. r9: raw-rcp activations + 4-chain combine (depth ~6 -> ~4).
template <int IN, bool FIRST, bool STORE>
__device__ void run_layer(const float4* __restrict__ wl, const float* __restrict__ bL,
                          const float* __restrict__ xsrc, float* __restrict__ hdst,
                          int b, int tid, int f, int rg, bool real,
                          float* xh, float4* part4) {
    // weights -> registers: branch-free, constant dest indices
    float2v w[40];  // [g*10 + 2q] = k pair (4q,4q+1), [g*10+2q+1] = (4q+2,4q+3)
#pragma unroll
    for (int g = 0; g < 4; ++g) {
#pragma unroll
        for (int q = 0; q < 5; ++q) {
            float4 t = wl[(g * 5 + q) * 1024 + tid];
            w[g * 10 + 2 * q]     = (float2v){t.x, t.y};
            w[g * 10 + 2 * q + 1] = (float2v){t.z, t.w};
        }
    }
    // combine threads hold their unit's biases in registers
    float bi = 0.f, bf = 0.f, bg = 0.f, bo = 0.f;
    if (tid < 100) {
        bi = bL[tid]; bf = bL[100 + tid]; bg = bL[200 + tid]; bo = bL[300 + tid];
    }

    if (tid < 256) xh[tid] = 0.f;
    __syncthreads();
    if (FIRST) {
        if (tid < 5) xh[tid] = xsrc[b * TSEQ * 5 + tid];
    } else {
        if (tid < 25) ((float4*)xh)[tid] = ((const float4*)xsrc)[b * TSEQ * 25 + tid];
    }
    __syncthreads();

    const float4* xv4 = (const float4*)xh + f * 5;  // chunk base (dummies -> zeros at 200+)
    float c = 0.f, hprev = 0.f;

    // layer 0: chunks f>=6 are all-zero weights -> those threads skip MAC entirely
    bool mac = FIRST ? (tid < 600) : real;

    for (int t = 0; t < TSEQ; ++t) {
        // delayed h-store: issued at phase top so the barrier drain finds it done
        if (STORE) {
            if (tid < 100 && t > 0) hdst[(b * TSEQ + (t - 1)) * 100 + tid] = hprev;
        }
        // prefetch next-step input (landed after combine)
        int tn = (t + 1 < TSEQ) ? (t + 1) : (TSEQ - 1);
        float pfs = 0.f;
        float4 pf4 = {0.f, 0.f, 0.f, 0.f};
        if (FIRST) {
            if (tid >= 128 && tid < 133) pfs = xsrc[(b * TSEQ + tn) * 5 + (tid - 128)];
        } else {
            if (tid >= 128 && tid < 153) pf4 = ((const float4*)xsrc)[(b * TSEQ + tn) * 25 + (tid - 128)];
        }

        // 80 MACs as 40 v_pk_fma_f32
        if (mac) {
            float2v a0 = {0.f, 0.f}, a1 = {0.f, 0.f}, a2 = {0.f, 0.f}, a3 = {0.f, 0.f};
#pragma unroll
            for (int q = 0; q < 5; ++q) {
                float4 xq = xv4[q];
                float2v xlo = (float2v){xq.x, xq.y};
                float2v xhi = (float2v){xq.z, xq.w};
                a0 = __builtin_elementwise_fma(w[2 * q],      xlo, a0);
                a0 = __builtin_elementwise_fma(w[2 * q + 1],  xhi, a0);
                a1 = __builtin_elementwise_fma(w[10 + 2 * q],     xlo, a1);
                a1 = __builtin_elementwise_fma(w[10 + 2 * q + 1], xhi, a1);
                a2 = __builtin_elementwise_fma(w[20 + 2 * q],     xlo, a2);
                a2 = __builtin_elementwise_fma(w[20 + 2 * q + 1], xhi, a2);
                a3 = __builtin_elementwise_fma(w[30 + 2 * q],     xlo, a3);
                a3 = __builtin_elementwise_fma(w[30 + 2 * q + 1], xhi, a3);
            }
            part4[f * 100 + rg] = make_float4(a0.x + a0.y, a1.x + a1.y,
                                              a2.x + a2.y, a3.x + a3.y);
        }
        __syncthreads();

        // combine: thread rg<100 owns unit rg end-to-end.
        // 4 independent accumulation chains (packed f2v), 2-level merge: depth ~4
        // over the part4 LDS-latency window instead of a serial 9-deep chain.
        if (tid < 100) {
            float4 p0 = part4[tid];
            float4 p1 = part4[100 + tid];
            float4 p2 = part4[200 + tid];
            float4 p3 = part4[300 + tid];
            float4 p4 = part4[400 + tid];
            float4 p5 = part4[500 + tid];
            float2v s0A = (float2v){p0.x, p0.y}, s0B = (float2v){p0.z, p0.w};
            float2v s1A = (float2v){p1.x, p1.y}, s1B = (float2v){p1.z, p1.w};
            float2v s2A = (float2v){p2.x, p2.y}, s2B = (float2v){p2.z, p2.w};
            float2v s3A = (float2v){p3.x, p3.y}, s3B = (float2v){p3.z, p3.w};
            s0A += (float2v){p4.x, p4.y}; s0B += (float2v){p4.z, p4.w};
            s1A += (float2v){p5.x, p5.y}; s1B += (float2v){p5.z, p5.w};
            if (!FIRST) {
                float4 p6 = part4[600 + tid];
                float4 p7 = part4[700 + tid];
                float4 p8 = part4[800 + tid];
                float4 p9 = part4[900 + tid];
                s2A += (float2v){p6.x, p6.y}; s2B += (float2v){p6.z, p6.w};
                s3A += (float2v){p7.x, p7.y}; s3B += (float2v){p7.z, p7.w};
                s0A += (float2v){p8.x, p8.y}; s0B += (float2v){p8.z, p8.w};
                s1A += (float2v){p9.x, p9.y}; s1B += (float2v){p9.z, p9.w};
            }
            float2v sA = (s0A + s2A) + (s1A + s3A);
            float2v sB = (s0B + s2B) + (s1B + s3B);
            float gi = sigmoid_(sA.x + bi);
            float gf = sigmoid_(sA.y + bf);
            float gg = tanh_(sB.x + bg);
            float go = sigmoid_(sB.y + bo);
            c = gf * c + gi * gg;
            float hv = go * tanh_(c);
            xh[IN + tid] = hv;
            hprev = hv;
        }
        // land prefetched x for t+1
        if (FIRST) {
            if (tid >= 128 && tid < 133) xh[tid - 128] = pfs;
        } else {
            if (tid >= 128 && tid < 153) ((float4*)xh)[tid - 128] = pf4;
        }
        __syncthreads();
    }
    if (STORE) {
        if (tid < 100) hdst[(b * TSEQ + TSEQ - 1) * 100 + tid] = hprev;
    }
}

extern "C" __global__ void __launch_bounds__(NT, 4)
gesture_lstm_kernel(const float* __restrict__ x,
                    const float4* __restrict__ wbuf,
                    const float* __restrict__ b0, const float* __restrict__ bLv,
                    const float* __restrict__ gamma, const float* __restrict__ beta,
                    const float* __restrict__ rmean, const float* __restrict__ rvar,
                    const float* __restrict__ W1, const float* __restrict__ b1,
                    const float* __restrict__ W2, const float* __restrict__ b2,
                    const float* __restrict__ W3, const float* __restrict__ b3,
                    float* __restrict__ out, float* __restrict__ hseq) {
    __shared__ __align__(16) float xh[256];
    __shared__ __align__(16) float4 part4[1000];
    __shared__ __align__(16) float hw[10000];

    int tid = threadIdx.x;
    int b = blockIdx.x;
    int f = tid / 100;   // 10 for dummies -> xv4 reads land in xh[200..220) (zeroed)
    int rg = tid % 100;
    bool real = tid < 1000;

    run_layer<5,   true,  true >(wbuf + 0 * 20480, b0,         x,    hseq, b, tid, f, rg, real, xh, part4);
    run_layer<100, false, true >(wbuf + 1 * 20480, bLv + 0,    hseq, hseq, b, tid, f, rg, real, xh, part4);
    run_layer<100, false, true >(wbuf + 2 * 20480, bLv + 400,  hseq, hseq, b, tid, f, rg, real, xh, part4);
    run_layer<100, false, true >(wbuf + 3 * 20480, bLv + 800,  hseq, hseq, b, tid, f, rg, real, xh, part4);
    run_layer<100, false, false>(wbuf + 4 * 20480, bLv + 1200, hseq, hseq, b, tid, f, rg, real, xh, part4);

    // ---- head: BN (inference) -> FC1+ReLU -> FC2+ReLU -> FC3 ----
    float* fcbuf = (float*)part4;
    if (tid < 100) {
        float hv = xh[100 + tid];
        xh[tid] = (hv - rmean[tid]) * rsqrtf(rvar[tid] + 1e-5f) * gamma[tid] + beta[tid];
    }
    __syncthreads();

    for (int i = tid; i < 2500; i += NT) ((float4*)hw)[i] = ((const float4*)W1)[i];
    __syncthreads();
    if (tid < 100) {
        float acc = b1[tid];
#pragma unroll
        for (int k = 0; k < 100; ++k) acc = fmaf(hw[tid * 100 + k], xh[k], acc);
        fcbuf[tid] = fmaxf(acc, 0.0f);
    }
    __syncthreads();

    for (int i = tid; i < 2500; i += NT) ((float4*)hw)[i] = ((const float4*)W2)[i];
    __syncthreads();
    if (tid < 100) {
        float acc = b2[tid];
#pragma unroll
        for (int k = 0; k < 100; ++k) acc = fmaf(hw[tid * 100 + k], fcbuf[k], acc);
        fcbuf[400 + tid] = fmaxf(acc, 0.0f);
    }
    __syncthreads();

    if (tid < 3) {
        float acc = b3[tid];
#pragma unroll
        for (int k = 0; k < 100; ++k) acc = fmaf(W3[tid * 100 + k], fcbuf[400 + k], acc);
        out[b * 3 + tid] = acc;
    }
}

extern "C" void kernel_launch(void* const* d_in, const int* in_sizes, int n_in,
                              void* d_out, int out_size, void* d_ws, size_t ws_size,
                              hipStream_t stream) {
    const float* x     = (const float*)d_in[0];
    const float* Wih0  = (const float*)d_in[1];
    const float* Whh0  = (const float*)d_in[2];
    const float* b0    = (const float*)d_in[3];
    const float* WihL  = (const float*)d_in[4];
    const float* WhhL  = (const float*)d_in[5];
    const float* bLv   = (const float*)d_in[6];
    const float* gamma = (const float*)d_in[7];
    const float* beta  = (const float*)d_in[8];
    const float* rmean = (const float*)d_in[9];
    const float* rvar  = (const float*)d_in[10];
    const float* W1    = (const float*)d_in[11];
    const float* b1    = (const float*)d_in[12];
    const float* W2    = (const float*)d_in[13];
    const float* b2    = (const float*)d_in[14];
    const float* W3    = (const float*)d_in[15];
    const float* b3    = (const float*)d_in[16];

    float4* wbuf = (float4*)d_ws;                       // 102400 float4 = 1.6375 MB
    float* hseq  = (float*)((char*)d_ws + 102400 * 16); // 256*512*100 fp32 = 52.4 MB

    prep_weights<<<dim3(400), dim3(256), 0, stream>>>(Wih0, Whh0, WihL, WhhL, wbuf);
    gesture_lstm_kernel<<<dim3(256), dim3(NT), 0, stream>>>(
        x, wbuf, b0, bLv, gamma, beta, rmean, rvar, W1, b1, W2, b2, W3, b3,
        (float*)d_out, hseq);
}